// Round 1
// baseline (55657.178 us; speedup 1.0000x reference)
//
#include <hip/hip_runtime.h>

#define IN_   16
#define HID_  50
#define G4_   200   // 4*HID
#define T_    128
#define NCLS_ 20
#define BPB_  16    // batches per block
#define NTHR_ 256

__device__ __forceinline__ float fast_sigmoid(float v) {
    float e = __expf(-v);                       // v->-inf: e=inf -> rcp=0; v->+inf: e=0 -> 1
    return __builtin_amdgcn_rcpf(1.0f + e);
}
__device__ __forceinline__ float fast_tanh(float v) {
    float e = __expf(2.0f * v);                 // inf/0 both give correct +-1
    return fmaf(-2.0f, __builtin_amdgcn_rcpf(e + 1.0f), 1.0f);
}

// 16 batch-fmas from one LDS row (broadcast float4 reads, conflict-free)
#define FMA16(RPTR, W) do {                                              \
    const float4* _r = (const float4*)(RPTR);                            \
    const float4 _r0 = _r[0], _r1 = _r[1], _r2 = _r[2], _r3 = _r[3];     \
    a[0]  = fmaf(_r0.x,(W),a[0]);  a[1]  = fmaf(_r0.y,(W),a[1]);         \
    a[2]  = fmaf(_r0.z,(W),a[2]);  a[3]  = fmaf(_r0.w,(W),a[3]);         \
    a[4]  = fmaf(_r1.x,(W),a[4]);  a[5]  = fmaf(_r1.y,(W),a[5]);         \
    a[6]  = fmaf(_r1.z,(W),a[6]);  a[7]  = fmaf(_r1.w,(W),a[7]);         \
    a[8]  = fmaf(_r2.x,(W),a[8]);  a[9]  = fmaf(_r2.y,(W),a[9]);         \
    a[10] = fmaf(_r2.z,(W),a[10]); a[11] = fmaf(_r2.w,(W),a[11]);        \
    a[12] = fmaf(_r3.x,(W),a[12]); a[13] = fmaf(_r3.y,(W),a[13]);        \
    a[14] = fmaf(_r3.z,(W),a[14]); a[15] = fmaf(_r3.w,(W),a[15]);        \
} while (0)

__global__ __launch_bounds__(NTHR_, 2)
void lstm_fused(const float* __restrict__ x,
                const float* __restrict__ W_ih,
                const float* __restrict__ W_hh,
                const float* __restrict__ b_ih,
                const float* __restrict__ b_hh,
                const float* __restrict__ W_fc,
                const float* __restrict__ b_fc,
                float* __restrict__ out)
{
    // h/x laid out [feature][batch] so gate threads read rows as broadcast float4s.
    __shared__ __align__(16) float h_lds[HID_][BPB_];
    __shared__ __align__(16) float x_lds[IN_][BPB_];
    __shared__ __align__(16) float g_lds[G4_][20];  // 16->20 pad: conflict-free float4 r/w

    const int tid = threadIdx.x;
    const int b0  = blockIdx.x * BPB_;

    // ---- gate-thread persistent weights (tid<200): whole row in VGPRs, loaded once
    float w_ih[IN_];
    float w_hh[HID_];
    float bias = 0.0f;
    if (tid < G4_) {
        #pragma unroll
        for (int i = 0; i < IN_; ++i)  w_ih[i] = W_ih[tid * IN_ + i];
        #pragma unroll
        for (int j = 0; j < HID_; ++j) w_hh[j] = W_hh[tid * HID_ + j];
        bias = b_ih[tid] + b_hh[tid];
    }

    // ---- update-thread state: unit uk = tid/4, batches ub..ub+3, c in registers
    const int uk = tid >> 2;
    const int ub = (tid & 3) << 2;
    float c0 = 0.f, c1 = 0.f, c2 = 0.f, c3 = 0.f;

    // zero h
    for (int idx = tid; idx < HID_ * BPB_; idx += NTHR_)
        ((float*)h_lds)[idx] = 0.0f;

    // ---- x loader mapping: 256 threads = 16 batches x 16 features, one elem/step
    const int xb = tid >> 4;
    const int xi = tid & 15;
    const float* xp = x + (size_t)(b0 + xb) * (T_ * IN_) + xi;
    x_lds[xi][xb] = xp[0];
    __syncthreads();

    for (int t = 0; t < T_; ++t) {
        // prefetch next step's x element (hidden under compute)
        float xv_next = 0.0f;
        if (t + 1 < T_) xv_next = xp[(size_t)(t + 1) * IN_];

        if (tid < G4_) {
            float a[BPB_];
            #pragma unroll
            for (int b = 0; b < BPB_; ++b) a[b] = bias;

            #pragma unroll
            for (int i = 0; i < IN_; ++i) {      // input projection on the fly
                const float w = w_ih[i];
                FMA16(&x_lds[i][0], w);
            }
            #pragma unroll
            for (int j = 0; j < HID_; ++j) {     // recurrent matmul
                const float w = w_hh[j];
                FMA16(&h_lds[j][0], w);
            }

            // activation: gates 0..99 = i,f (sigmoid), 100..149 = g (tanh), 150..199 = o
            const bool isg = (tid >= 100) && (tid < 150);
            float act[BPB_];
            #pragma unroll
            for (int b = 0; b < BPB_; ++b)
                act[b] = isg ? fast_tanh(a[b]) : fast_sigmoid(a[b]);

            *(float4*)(&g_lds[tid][0])  = make_float4(act[0],  act[1],  act[2],  act[3]);
            *(float4*)(&g_lds[tid][4])  = make_float4(act[4],  act[5],  act[6],  act[7]);
            *(float4*)(&g_lds[tid][8])  = make_float4(act[8],  act[9],  act[10], act[11]);
            *(float4*)(&g_lds[tid][12]) = make_float4(act[12], act[13], act[14], act[15]);
        }
        __syncthreads();   // gates ready

        if (tid < G4_) {
            const float4 iv = *(const float4*)(&g_lds[uk       ][ub]);
            const float4 fv = *(const float4*)(&g_lds[ 50 + uk ][ub]);
            const float4 gv = *(const float4*)(&g_lds[100 + uk ][ub]);
            const float4 ov = *(const float4*)(&g_lds[150 + uk ][ub]);
            c0 = fmaf(fv.x, c0, iv.x * gv.x);
            c1 = fmaf(fv.y, c1, iv.y * gv.y);
            c2 = fmaf(fv.z, c2, iv.z * gv.z);
            c3 = fmaf(fv.w, c3, iv.w * gv.w);
            float4 hv;
            hv.x = ov.x * fast_tanh(c0);
            hv.y = ov.y * fast_tanh(c1);
            hv.z = ov.z * fast_tanh(c2);
            hv.w = ov.w * fast_tanh(c3);
            *(float4*)(&h_lds[uk][ub]) = hv;
        }
        x_lds[xi][xb] = xv_next;   // x_lds already consumed before barrier above
        __syncthreads();           // h + next x ready
    }

    // ---- FC head: 16 batches x 20 classes per block
    for (int p = tid; p < BPB_ * NCLS_; p += NTHR_) {
        const int b  = p / NCLS_;
        const int cl = p % NCLS_;
        float acc = b_fc[cl];
        #pragma unroll
        for (int j = 0; j < HID_; ++j) {
            float hv = fmaxf(h_lds[j][b], 0.0f);   // relu
            acc = fmaf(hv, W_fc[cl * HID_ + j], acc);
        }
        out[(size_t)(b0 + b) * NCLS_ + cl] = acc;
    }
}

extern "C" void kernel_launch(void* const* d_in, const int* in_sizes, int n_in,
                              void* d_out, int out_size, void* d_ws, size_t ws_size,
                              hipStream_t stream) {
    const float* x    = (const float*)d_in[0];
    const float* W_ih = (const float*)d_in[1];
    const float* W_hh = (const float*)d_in[2];
    const float* b_ih = (const float*)d_in[3];
    const float* b_hh = (const float*)d_in[4];
    const float* W_fc = (const float*)d_in[5];
    const float* b_fc = (const float*)d_in[6];
    float* out = (float*)d_out;

    const int B = in_sizes[0] / (T_ * IN_);   // 8192
    dim3 grid(B / BPB_), block(NTHR_);
    hipLaunchKernelGGL(lstm_fused, grid, block, 0, stream,
                       x, W_ih, W_hh, b_ih, b_hh, W_fc, b_fc, out);
}

// Round 2
// 55152.991 us; speedup vs baseline: 1.0091x; 1.0091x over previous
//
#include <hip/hip_runtime.h>

#define IN_   16
#define HID_  50
#define G4_   200   // 4*HID
#define T_    128
#define NCLS_ 20
#define BPB_  16    // batches per block
#define NTHR_ 256
#define WPAD_ 51    // W_hh LDS row stride (odd -> conflict-free)
#define GPAD_ 17    // gate LDS row stride (odd -> conflict-free)

__device__ __forceinline__ float fast_sigmoid(float v) {
    float e = __expf(-v);
    return __builtin_amdgcn_rcpf(1.0f + e);
}
__device__ __forceinline__ float fast_tanh(float v) {
    float e = __expf(2.0f * v);
    return fmaf(-2.0f, __builtin_amdgcn_rcpf(e + 1.0f), 1.0f);
}

// 16 batch-fmas from one LDS row (broadcast float4 reads, conflict-free)
#define FMA16(RPTR, W) do {                                              \
    const float4* _r = (const float4*)(RPTR);                            \
    const float4 _r0 = _r[0], _r1 = _r[1], _r2 = _r[2], _r3 = _r[3];     \
    a[0]  = fmaf(_r0.x,(W),a[0]);  a[1]  = fmaf(_r0.y,(W),a[1]);         \
    a[2]  = fmaf(_r0.z,(W),a[2]);  a[3]  = fmaf(_r0.w,(W),a[3]);         \
    a[4]  = fmaf(_r1.x,(W),a[4]);  a[5]  = fmaf(_r1.y,(W),a[5]);         \
    a[6]  = fmaf(_r1.z,(W),a[6]);  a[7]  = fmaf(_r1.w,(W),a[7]);         \
    a[8]  = fmaf(_r2.x,(W),a[8]);  a[9]  = fmaf(_r2.y,(W),a[9]);         \
    a[10] = fmaf(_r2.z,(W),a[10]); a[11] = fmaf(_r2.w,(W),a[11]);        \
    a[12] = fmaf(_r3.x,(W),a[12]); a[13] = fmaf(_r3.y,(W),a[13]);        \
    a[14] = fmaf(_r3.z,(W),a[14]); a[15] = fmaf(_r3.w,(W),a[15]);        \
} while (0)

__global__ __launch_bounds__(NTHR_, 2)
void lstm_fused(const float* __restrict__ x,
                const float* __restrict__ W_ih,
                const float* __restrict__ W_hh,
                const float* __restrict__ b_ih,
                const float* __restrict__ b_hh,
                const float* __restrict__ W_fc,
                const float* __restrict__ b_fc,
                float* __restrict__ out)
{
    // h/x laid out [feature][batch] so gate threads read rows as broadcast float4s.
    __shared__ __align__(16) float h_lds[HID_][BPB_];
    __shared__ __align__(16) float x_lds[IN_][BPB_];
    __shared__ float g_lds[G4_][GPAD_];     // scalar r/w, odd stride -> conflict-free
    __shared__ float whh_lds[G4_ * WPAD_];  // W_hh rows, stride 51

    const int tid = threadIdx.x;
    const int b0  = blockIdx.x * BPB_;

    // ---- stage W_hh into LDS (coalesced global read, padded LDS write), one time
    for (int idx = tid; idx < G4_ * HID_; idx += NTHR_) {
        const int r = idx / HID_;
        const int c = idx - r * HID_;
        whh_lds[r * WPAD_ + c] = W_hh[idx];
    }

    // ---- gate-thread registers: only W_ih row (16) + bias stay persistent
    float w_ih[IN_];
    float bias = 0.0f;
    if (tid < G4_) {
        #pragma unroll
        for (int i = 0; i < IN_; ++i)  w_ih[i] = W_ih[tid * IN_ + i];
        bias = b_ih[tid] + b_hh[tid];
    }

    // ---- update-thread state: unit uk = tid/4, batches ub..ub+3, c in registers
    const int uk = tid >> 2;
    const int ub = (tid & 3) << 2;
    float c0 = 0.f, c1 = 0.f, c2 = 0.f, c3 = 0.f;

    // zero h
    for (int idx = tid; idx < HID_ * BPB_; idx += NTHR_)
        ((float*)h_lds)[idx] = 0.0f;

    // ---- x loader mapping: 256 threads = 16 batches x 16 features, one elem/step
    const int xb = tid >> 4;
    const int xi = tid & 15;
    const float* xp = x + (size_t)(b0 + xb) * (T_ * IN_) + xi;
    x_lds[xi][xb] = xp[0];
    __syncthreads();

    const float* wr = &whh_lds[tid * WPAD_];   // this gate's W_hh row (LDS)

    for (int t = 0; t < T_; ++t) {
        // prefetch next step's x element (hidden under compute)
        float xv_next = 0.0f;
        if (t + 1 < T_) xv_next = xp[(size_t)(t + 1) * IN_];

        if (tid < G4_) {
            float a[BPB_];
            #pragma unroll
            for (int b = 0; b < BPB_; ++b) a[b] = bias;

            #pragma unroll
            for (int i = 0; i < IN_; ++i) {      // input projection on the fly
                const float w = w_ih[i];
                FMA16(&x_lds[i][0], w);
            }
            #pragma unroll
            for (int j = 0; j < HID_; ++j) {     // recurrent matmul, weights from LDS
                const float w = wr[j];
                FMA16(&h_lds[j][0], w);
            }

            // activation in place: 0..99 = i,f (sigmoid), 100..149 = g (tanh), 150..199 = o
            const bool isg = (tid >= 100) && (tid < 150);
            #pragma unroll
            for (int b = 0; b < BPB_; ++b)
                a[b] = isg ? fast_tanh(a[b]) : fast_sigmoid(a[b]);

            #pragma unroll
            for (int b = 0; b < BPB_; ++b)
                g_lds[tid][b] = a[b];
        }
        __syncthreads();   // gates ready

        if (tid < G4_) {
            float iv[4], fv[4], gv[4], ov[4];
            #pragma unroll
            for (int k = 0; k < 4; ++k) {
                iv[k] = g_lds[uk      ][ub + k];
                fv[k] = g_lds[ 50 + uk][ub + k];
                gv[k] = g_lds[100 + uk][ub + k];
                ov[k] = g_lds[150 + uk][ub + k];
            }
            c0 = fmaf(fv[0], c0, iv[0] * gv[0]);
            c1 = fmaf(fv[1], c1, iv[1] * gv[1]);
            c2 = fmaf(fv[2], c2, iv[2] * gv[2]);
            c3 = fmaf(fv[3], c3, iv[3] * gv[3]);
            float4 hv;
            hv.x = ov[0] * fast_tanh(c0);
            hv.y = ov[1] * fast_tanh(c1);
            hv.z = ov[2] * fast_tanh(c2);
            hv.w = ov[3] * fast_tanh(c3);
            *(float4*)(&h_lds[uk][ub]) = hv;
        }
        x_lds[xi][xb] = xv_next;   // x_lds already consumed before barrier above
        __syncthreads();           // h + next x ready
    }

    // ---- FC head: 16 batches x 20 classes per block
    for (int p = tid; p < BPB_ * NCLS_; p += NTHR_) {
        const int b  = p / NCLS_;
        const int cl = p % NCLS_;
        float acc = b_fc[cl];
        #pragma unroll
        for (int j = 0; j < HID_; ++j) {
            float hv = fmaxf(h_lds[j][b], 0.0f);   // relu
            acc = fmaf(hv, W_fc[cl * HID_ + j], acc);
        }
        out[(size_t)(b0 + b) * NCLS_ + cl] = acc;
    }
}

extern "C" void kernel_launch(void* const* d_in, const int* in_sizes, int n_in,
                              void* d_out, int out_size, void* d_ws, size_t ws_size,
                              hipStream_t stream) {
    const float* x    = (const float*)d_in[0];
    const float* W_ih = (const float*)d_in[1];
    const float* W_hh = (const float*)d_in[2];
    const float* b_ih = (const float*)d_in[3];
    const float* b_hh = (const float*)d_in[4];
    const float* W_fc = (const float*)d_in[5];
    const float* b_fc = (const float*)d_in[6];
    float* out = (float*)d_out;

    const int B = in_sizes[0] / (T_ * IN_);   // 8192
    dim3 grid(B / BPB_), block(NTHR_);
    hipLaunchKernelGGL(lstm_fused, grid, block, 0, stream,
                       x, W_ih, W_hh, b_ih, b_hh, W_fc, b_fc, out);
}